// Round 17
// baseline (69.968 us; speedup 1.0000x reference)
//
#include <hip/hip_runtime.h>
#include <math.h>

#define B_ 64
#define N_ 200
#define P_ 400
#define T_ 1200
#define TPAD 1280
#define PPAD 512
#define STRIDE_ 25
#define EPS_ 1e-9f
#define KPAD 224

// ws layout (float offsets)
#define OFF_NPATT  0            // [N_][P_] f32 (fallback orth path)
#define OFF_NPB16  80000        // [P_][KPAD] bf16 row-major patterns
#define OFF_KEYVAL 124800       // [P_][4]
#define OFF_KEYIDX 126400       // [P_][4] int
#define OFF_PES    128000       // [B_][P_] (fallback only)
#define OFF_NORMB  153600       // [100] per-pat-block norm partials
#define OFF_ORTHB  153700       // [20] per-orth-block partials
#define OFF_NORM   OFF_NORMB    // fallback scalar slot
#define OFF_ORTH   OFF_ORTHB
#define OFF_NPBT   153728       // [28][PPAD][8] bf16 K-outer patterns (57344 f32)
#define OFF_XN     211072       // [B_][28][TPAD][8] bf16 K-outer frames (9175040 f32)
#define OFF_GPOOL  9386112      // [2][B_][10mb][7][400] okey uints (3,584,000)
#define WS_FAST_FLOATS (9386112 + 3584000)

// prep block roles
#define ZP_BLKS  2              // zero npbT pad rows
#define PAT_BLKS 100
#define TN_BLKS  (20 * B_)      // 1280
#define Z_ALL    ZP_BLKS
#define PREP_BLKS (Z_ALL + PAT_BLKS + TN_BLKS)

typedef float f4v __attribute__((ext_vector_type(4)));
typedef short s8v __attribute__((ext_vector_type(8)));

__device__ inline unsigned short f2bf(float f) {
    union { float f; unsigned u; } v; v.f = f;
    unsigned r = v.u + 0x7FFFu + ((v.u >> 16) & 1u);
    return (unsigned short)(r >> 16);
}
__device__ inline unsigned okey(float f) {
    unsigned u = __float_as_uint(f);
    return (u & 0x80000000u) ? ~u : (u | 0x80000000u);
}
__device__ inline float dekey(unsigned k) {
    unsigned u = (k & 0x80000000u) ? (k & 0x7fffffffu) : ~k;
    return __uint_as_float(u);
}

// ======= pat body (one wave, one pattern). Returns lane0's norm term. =======
__device__ float pat_body(const float* __restrict__ patterns, float* __restrict__ ws,
                          int p, int lane) {
    float v0 = patterns[p * N_ + lane];
    float v1 = patterns[p * N_ + lane + 64];
    float v2 = patterns[p * N_ + lane + 128];
    float v3 = (lane < 8) ? patterns[p * N_ + lane + 192] : 0.0f;

    float ss = v0 * v0 + v1 * v1 + v2 * v2 + v3 * v3;
    for (int off = 32; off; off >>= 1) ss += __shfl_down(ss, off);
    ss = __shfl(ss, 0);

    float rn = 1.0f / sqrtf(ss + EPS_);
    float s0 = v0 * rn, s1 = v1 * rn, s2 = v2 * rn, s3 = v3 * rn;

    float* npatT = ws + OFF_NPATT;
    npatT[(lane) * P_ + p] = s0;
    npatT[(lane + 64) * P_ + p] = s1;
    npatT[(lane + 128) * P_ + p] = s2;
    if (lane < 8) npatT[(lane + 192) * P_ + p] = s3;

    unsigned short* npb = (unsigned short*)(ws + OFF_NPB16);
    unsigned short b0 = f2bf(s0), b1 = f2bf(s1), b2 = f2bf(s2), b3 = f2bf(s3);
    npb[p * KPAD + lane] = b0;
    npb[p * KPAD + lane + 64] = b1;
    npb[p * KPAD + lane + 128] = b2;
    if (lane < 8) npb[p * KPAD + lane + 192] = b3;
    if (lane < 24) npb[p * KPAD + 200 + lane] = 0;

    unsigned short* npbT = (unsigned short*)(ws + OFF_NPBT);
    {
        int k0 = lane, k1 = lane + 64, k2 = lane + 128;
        npbT[(k0 >> 3) * (PPAD * 8) + p * 8 + (k0 & 7)] = b0;
        npbT[(k1 >> 3) * (PPAD * 8) + p * 8 + (k1 & 7)] = b1;
        npbT[(k2 >> 3) * (PPAD * 8) + p * 8 + (k2 & 7)] = b2;
        if (lane < 8) {
            int k3 = lane + 192;
            npbT[(k3 >> 3) * (PPAD * 8) + p * 8 + (k3 & 7)] = b3;
        }
        if (lane < 24) {
            int k4 = 200 + lane;
            npbT[(k4 >> 3) * (PPAD * 8) + p * 8 + (k4 & 7)] = 0;
        }
    }

    float a0 = fabsf(s0), a1 = fabsf(s1), a2 = fabsf(s2), a3 = fabsf(s3);

    int ch0 = -1, ch1 = -1, ch2 = -1;
    float cs0 = 0.f, cs1 = 0.f, cs2 = 0.f;

    for (int r = 0; r < 3; r++) {
        float bv = -1.0f;
        int bi = 1 << 30;
        {
            int n = lane;
            bool sk = (n == ch0) || (n == ch1) || (n == ch2);
            if (!sk && a0 > bv) { bv = a0; bi = n; }
        }
        {
            int n = lane + 64;
            bool sk = (n == ch0) || (n == ch1) || (n == ch2);
            if (!sk && (a1 > bv || (a1 == bv && n < bi))) { bv = a1; bi = n; }
        }
        {
            int n = lane + 128;
            bool sk = (n == ch0) || (n == ch1) || (n == ch2);
            if (!sk && (a2 > bv || (a2 == bv && n < bi))) { bv = a2; bi = n; }
        }
        if (lane < 8) {
            int n = lane + 192;
            bool sk = (n == ch0) || (n == ch1) || (n == ch2);
            if (!sk && (a3 > bv || (a3 == bv && n < bi))) { bv = a3; bi = n; }
        }
        for (int off = 32; off; off >>= 1) {
            float ov = __shfl_down(bv, off);
            int oi = __shfl_down(bi, off);
            if (ov > bv || (ov == bv && oi < bi)) { bv = ov; bi = oi; }
        }
        bi = __shfl(bi, 0);
        int slot = bi >> 6, src = bi & 63;
        float mine = (slot == 0) ? s0 : (slot == 1) ? s1 : (slot == 2) ? s2 : s3;
        float sval = __shfl(mine, src);
        if (r == 0) { ch0 = bi; cs0 = sval; }
        else if (r == 1) { ch1 = bi; cs1 = sval; }
        else { ch2 = bi; cs2 = sval; }
    }

    float d2 = 0.f;
    if (lane == 0) {
        float* keyval = ws + OFF_KEYVAL;
        int* keyidx = (int*)(ws + OFF_KEYIDX);
        keyval[p * 4 + 0] = cs0; keyval[p * 4 + 1] = cs1; keyval[p * 4 + 2] = cs2;
        keyval[p * 4 + 3] = 0.f;
        keyidx[p * 4 + 0] = ch0; keyidx[p * 4 + 1] = ch1; keyidx[p * 4 + 2] = ch2;
        keyidx[p * 4 + 3] = -1;
        float lenp = sqrtf(ss) * rn;
        float lentopp = sqrtf(cs0 * cs0 + cs1 * cs1 + cs2 * cs2);
        float d = 1.0f - lentopp / lenp;
        d2 = d * d * (1.0f / (float)P_);
    }
    return d2;
}

// == prep: zero npbT-pad (0..1) + pat (2..101) + tnorm (102..1381) ===========
__global__ __launch_bounds__(256) void prep_kernel(const float* __restrict__ x,
                                                   const float* __restrict__ patterns,
                                                   float* __restrict__ ws) {
    __shared__ unsigned short xt16[64 * 210];
    __shared__ float psums[256];
    __shared__ float rns[64];
    __shared__ float sh4[4];

    const int tid = threadIdx.x;

    if (blockIdx.x < Z_ALL) {
        unsigned* p32 = (unsigned*)(ws + OFF_NPBT);
        int lb = blockIdx.x;
        for (int e = lb * 256 + tid; e < 12544; e += ZP_BLKS * 256) {
            int seg = e / 448, r32 = e % 448;
            p32[seg * 2048 + 1600 + r32] = 0u;
        }
        return;
    }

    if (blockIdx.x < Z_ALL + PAT_BLKS) {
        int pblk = blockIdx.x - Z_ALL;
        int wv = tid >> 6, lane = tid & 63;
        int p = pblk * 4 + wv;
        float d2 = pat_body(patterns, ws, p, lane);
        if (lane == 0) sh4[wv] = d2;
        __syncthreads();
        if (tid == 0)
            ws[OFF_NORMB + pblk] = sh4[0] + sh4[1] + sh4[2] + sh4[3];
        return;
    }

    const int blk = blockIdx.x - Z_ALL - PAT_BLKS;
    const int t = tid & 63, r = tid >> 6;
    const int b = blk / 20;
    const int t0 = (blk % 20) * 64;
    const bool valid = (t0 + t) < T_;

    float ss = 0.0f;
    if (valid) {
        const float* xp = x + (size_t)b * N_ * T_ + t0 + t;
#pragma unroll 5
        for (int i = 0; i < 50; ++i) {
            int n = r * 50 + i;
            float v = xp[(size_t)n * T_];
            ss += v * v;
            xt16[t * 210 + n] = f2bf(v);
        }
    }
    psums[tid] = ss;
    __syncthreads();
    if (tid < 64) {
        float s = psums[tid] + psums[tid + 64] + psums[tid + 128] + psums[tid + 192];
        rns[tid] = rsqrtf(s + EPS_);
    }
    __syncthreads();

    unsigned short* xnT = (unsigned short*)(ws + OFF_XN);
#pragma unroll
    for (int j = 0; j < 7; ++j) {
        int idx = tid + 256 * j;
        int seg = idx >> 6, tt = idx & 63;
        s8v ov = (s8v){0, 0, 0, 0, 0, 0, 0, 0};
        if (seg < 25 && (t0 + tt) < T_) {
            float rn = rns[tt];
            const unsigned* src = (const unsigned*)&xt16[tt * 210 + seg * 8];
            unsigned o[4];
#pragma unroll
            for (int i = 0; i < 4; ++i) {
                unsigned u = src[i];
                float lo = __uint_as_float(u << 16) * rn;
                float hi = __uint_as_float(u & 0xffff0000u) * rn;
                o[i] = (unsigned)f2bf(lo) | ((unsigned)f2bf(hi) << 16);
            }
            ov = (s8v){(short)(o[0] & 0xffff), (short)(o[0] >> 16),
                       (short)(o[1] & 0xffff), (short)(o[1] >> 16),
                       (short)(o[2] & 0xffff), (short)(o[2] >> 16),
                       (short)(o[3] & 0xffff), (short)(o[3] >> 16)};
        }
        *(s8v*)(xnT + (((size_t)b * 28 + seg) * TPAD + t0 + tt) * 8) = ov;
    }
}

// ======= work: gemm (nid 0..639, 5 mb-tiles each) + orth (640..659) =========
// ldsB [80][224] bf16, XOR-swizzled (short_idx ^= ((row&3)<<3)) -> 40320 B
// total LDS -> 4 blocks/CU. Pool slices EXCLUSIVE per (pb,mb,b).
__global__ __launch_bounds__(256, 4) void work_kernel(float* __restrict__ ws,
                                                      unsigned* __restrict__ gpool) {
    __shared__ short ldsB[80 * 224];           // 35.84 KB
    __shared__ unsigned pool[2 * 7 * 80];      // 4.48 KB

    const int tid = threadIdx.x;
    const unsigned OKNEG = okey(-1e30f);
    int orig = blockIdx.x;
    int xcd = orig & 7, rem = orig >> 3;
    int nid = (xcd < 4 ? xcd * 83 : 4 * 83 + (xcd - 4) * 82) + rem;

    const bool isOrth = (nid >= 640);
    int pb, mbg, b;
    if (isOrth) { int o = nid - 640; pb = o % 5; mbg = o / 5; b = 0; }
    else        { pb = nid % 5; mbg = (nid / 5) % 2; b = nid / 10; }

    const unsigned short* npb = (const unsigned short*)(ws + OFF_NPB16) + (size_t)(pb * 80) * KPAD;

    // stage B once (swizzled): 80 rows x 28 16B-units
#pragma unroll
    for (int j = 0; j < 9; ++j) {
        int idx = tid + 256 * j;
        if (idx < 2240) {
            int row = idx / 28, seg = idx % 28;
            int off = row * 224 + ((seg * 8) ^ ((row & 3) << 3));
            *(s8v*)(&ldsB[off]) = *(const s8v*)(npb + (size_t)row * KPAD + seg * 8);
        }
    }
    for (int i = tid; i < 1120; i += 256) pool[i] = OKNEG;
    __syncthreads();

    const int wv = tid >> 6;
    const int lane = tid & 63;
    const int l15 = lane & 15, kg = lane >> 4;
    const int bswz = (l15 & 3) << 3;           // row&3 == l15&3 (rows = ni*16+l15)

    const int ROWS = isOrth ? PPAD : TPAD;
    const unsigned short* abase = isOrth
        ? (const unsigned short*)(ws + OFF_NPBT)
        : (const unsigned short*)(ws + OFF_XN) + (size_t)b * 28 * TPAD * 8;
    const int segstep = 4 * ROWS * 8;
    const int niter = isOrth ? 1 : 5;

    float orthpart = 0.f;

    for (int it = 0; it < niter; ++it) {
        const int mb = isOrth ? mbg : (mbg * 5 + it);
        const int row0 = mb * 128 + wv * 32 + l15;
        const unsigned short* ar0 = abase + ((size_t)kg * ROWS + row0) * 8;
        const unsigned short* ar1 = ar0 + 16 * 8;

        f4v acc[2][5];
#pragma unroll
        for (int mi = 0; mi < 2; ++mi)
#pragma unroll
            for (int ni = 0; ni < 5; ++ni) acc[mi][ni] = (f4v){0.f, 0.f, 0.f, 0.f};

        s8v A[4][2];
#pragma unroll
        for (int c = 0; c < 4; ++c) {
            A[c][0] = *(const s8v*)(ar0 + c * segstep);
            A[c][1] = *(const s8v*)(ar1 + c * segstep);
        }

#pragma unroll
        for (int c = 0; c < 7; ++c) {
            if (c + 4 < 7) {
                A[(c + 4) & 3][0] = *(const s8v*)(ar0 + (c + 4) * segstep);
                A[(c + 4) & 3][1] = *(const s8v*)(ar1 + (c + 4) * segstep);
            }
            s8v bf[5];
#pragma unroll
            for (int ni = 0; ni < 5; ++ni)
                bf[ni] = *(const s8v*)(&ldsB[(ni * 16 + l15) * 224 + ((c * 32 + kg * 8) ^ bswz)]);
#pragma unroll
            for (int ni = 0; ni < 5; ++ni) {
                acc[0][ni] = __builtin_amdgcn_mfma_f32_16x16x32_bf16(A[c & 3][0], bf[ni], acc[0][ni], 0, 0, 0);
                acc[1][ni] = __builtin_amdgcn_mfma_f32_16x16x32_bf16(A[c & 3][1], bf[ni], acc[1][ni], 0, 0, 0);
            }
        }

        if (isOrth) {
#pragma unroll
            for (int mi = 0; mi < 2; ++mi) {
                int rb = mb * 128 + wv * 32 + mi * 16 + kg * 4;
#pragma unroll
                for (int ni = 0; ni < 5; ++ni) {
                    int col = pb * 80 + ni * 16 + l15;
#pragma unroll
                    for (int jj = 0; jj < 4; ++jj) {
                        if (rb + jj == col) continue;
                        float t = (fabsf(acc[mi][ni][jj]) - 0.3f) * (1.0f / 0.70001f);
                        if (t > 0.0f) orthpart += t * t;
                    }
                }
            }
            break;
        }

        const int wbase = (mb * 128) / 25;
#pragma unroll
        for (int mi = 0; mi < 2; ++mi) {
            int f0 = mb * 128 + wv * 32 + mi * 16 + kg * 4;
            int w0 = f0 / 25, w3 = (f0 + 3) / 25;
            int wsplit = w3 * 25;
#pragma unroll
            for (int ni = 0; ni < 5; ++ni) {
                int pc = ni * 16 + l15;
                float p0 = -1e30f, p1 = -1e30f, n0 = -1e30f, n1 = -1e30f;
#pragma unroll
                for (int jj = 0; jj < 4; ++jj) {
                    float v = acc[mi][ni][jj];
                    if (f0 + jj < wsplit) { p0 = fmaxf(p0, v); n0 = fmaxf(n0, -v); }
                    else                 { p1 = fmaxf(p1, v); n1 = fmaxf(n1, -v); }
                }
                atomicMax(&pool[(0 * 7 + (w3 - wbase)) * 80 + pc], okey(p1));
                atomicMax(&pool[(1 * 7 + (w3 - wbase)) * 80 + pc], okey(n1));
                if (w0 != w3) {
                    atomicMax(&pool[(0 * 7 + (w0 - wbase)) * 80 + pc], okey(p0));
                    atomicMax(&pool[(1 * 7 + (w0 - wbase)) * 80 + pc], okey(n0));
                }
            }
        }
        __syncthreads();
        for (int e = tid; e < 1120; e += 256) {
            int pass = e / 560, r2 = e % 560;
            int slot = r2 / 80, pp = r2 % 80;
            gpool[(((size_t)(pass * B_ + b)) * 10 + mb) * 2800 + slot * 400 + pb * 80 + pp] = pool[e];
            pool[e] = OKNEG;
        }
        __syncthreads();
    }

    if (isOrth) {
        for (int off = 32; off; off >>= 1) orthpart += __shfl_down(orthpart, off);
        __syncthreads();
        float* red = (float*)pool;
        if (lane == 0) red[wv] = orthpart;
        __syncthreads();
        if (tid == 0)
            ws[OFF_ORTHB + (nid - 640)] = (red[0] + red[1] + red[2] + red[3]) *
                                          (1.0f / ((float)P_ * (float)P_));
    }
}

// ======= graphs_row: PES merge (pes folded in) + row-gather + NT stream =====
// 256 blocks: b = blk/4, rows n0 = (blk%4)*50.
__global__ __launch_bounds__(256) void graphs_row_kernel(const unsigned* __restrict__ gpool,
                                                         const int* __restrict__ length,
                                                         const float* __restrict__ ws,
                                                         float* __restrict__ out) {
    __shared__ float rowbuf[50 * 200];     // 40 KB
    __shared__ int   ki[400][4];           // 6.4 KB
    __shared__ float kv[400][4];           // 6.4 KB
    __shared__ float el[400];              // 1.6 KB

    const int tid = threadIdx.x;
    const int b = blockIdx.x >> 2;
    const int n0 = (blockIdx.x & 3) * 50;

    for (int i = tid; i < 10000; i += 256) rowbuf[i] = 0.f;
    for (int p = tid; p < 400; p += 256) {
        *(int4*)ki[p] = ((const int4*)(ws + OFF_KEYIDX))[p];
        *(float4*)kv[p] = ((const float4*)(ws + OFF_KEYVAL))[p];
    }

    // PES merge (identical math/order to the former pes_kernel)
    float rsap = 1.0f / (float)(length[b] / STRIDE_);
    for (int p = tid; p < 400; p += 256) {
        float s = 0.f;
#pragma unroll
        for (int pass = 0; pass < 2; ++pass) {
            const unsigned* gp = gpool + ((size_t)(pass * B_ + b)) * 10 * 2800 + p;
            unsigned v[10][7];
#pragma unroll
            for (int mb = 0; mb < 10; ++mb)
#pragma unroll
                for (int sl = 0; sl < 7; ++sl)
                    v[mb][sl] = gp[mb * 2800 + sl * 400];
#pragma unroll
            for (int w = 0; w < 48; ++w) {
                int a = 25 * w - 127;
                int mb_lo = (a <= 0) ? 0 : ((a + 127) >> 7);
                int mb_hi = (25 * w + 24) >> 7;
                if (mb_hi > 9) mb_hi = 9;
                unsigned k = 0u;
#pragma unroll
                for (int mb = 0; mb < 10; ++mb) {
                    if (mb < mb_lo || mb > mb_hi) continue;
                    int slot = w - (mb * 128) / 25;
                    unsigned vv = v[mb][slot];
                    k = (vv > k) ? vv : k;
                }
                s += dekey(k);
            }
        }
        el[p] = s * 0.5f * rsap;
    }
    __syncthreads();

    for (int p = tid; p < 400; p += 256) {
        float e = el[p];
#pragma unroll
        for (int a = 0; a < 3; ++a) {
            int n = ki[p][a];
            if (n < n0 || n >= n0 + 50) continue;
            float va = kv[p][a] * e;
#pragma unroll
            for (int c = 0; c < 3; ++c) {
                float scale = (a == c) ? 1.0f : 6.0f;
                atomicAdd(&rowbuf[(n - n0) * 200 + ki[p][c]], va * kv[p][c] * scale);
            }
        }
    }
    __syncthreads();

    f4v* dst = (f4v*)(out + (size_t)b * N_ * N_ + (size_t)n0 * N_);
    const f4v* srcb = (const f4v*)rowbuf;
    for (int i = tid; i < 2500; i += 256)
        __builtin_nontemporal_store(srcb[i], dst + i);

    if (blockIdx.x == 0 && tid == 0) {
        float sn = 0.f;
        for (int i = 0; i < PAT_BLKS; ++i) sn += ws[OFF_NORMB + i];
        float so = 0.f;
        for (int i = 0; i < 20; ++i) so += ws[OFF_ORTHB + i];
        out[(size_t)B_ * N_ * N_] = sn;
        out[(size_t)B_ * N_ * N_ + 1] = so;
    }
}

// ---------------- fallback path (fp32, ws-size independent) -----------------
__global__ __launch_bounds__(256) void main_kernel(const float* __restrict__ x,
                                                   const int* __restrict__ length,
                                                   const float* __restrict__ ws,
                                                   float* __restrict__ pes) {
    __shared__ float xs[N_][STRIDE_ + 1];
    __shared__ float rnorm[STRIDE_];
    __shared__ float poolp[P_][5];
    __shared__ float pooln[P_][5];

    int w = blockIdx.x;
    int b = blockIdx.y;
    const float* xb = x + (size_t)b * N_ * T_ + (size_t)w * STRIDE_;

    for (int i = threadIdx.x; i < N_ * STRIDE_; i += 256) {
        int n = i / STRIDE_;
        int t = i - n * STRIDE_;
        xs[n][t] = xb[n * T_ + t];
    }
    __syncthreads();

    if (threadIdx.x < STRIDE_) {
        float ssf = 0.0f;
        for (int n = 0; n < N_; n++) { float vv = xs[n][threadIdx.x]; ssf += vv * vv; }
        rnorm[threadIdx.x] = 1.0f / sqrtf(ssf + EPS_);
    }
    __syncthreads();

    int pt = threadIdx.x % 50;
    int tt = threadIdx.x / 50;

    if (tt < 5) {
        float acc[8][5];
#pragma unroll
        for (int i = 0; i < 8; i++)
#pragma unroll
            for (int j = 0; j < 5; j++) acc[i][j] = 0.0f;

        const float4* np4 = (const float4*)(ws + OFF_NPATT);
        int pbq = pt * 2;
        for (int n = 0; n < N_; n++) {
            float4 q0 = np4[n * (P_ / 4) + pbq];
            float4 q1 = np4[n * (P_ / 4) + pbq + 1];
            float qa[8] = { q0.x, q0.y, q0.z, q0.w, q1.x, q1.y, q1.z, q1.w };
            float xv0 = xs[n][tt * 5 + 0];
            float xv1 = xs[n][tt * 5 + 1];
            float xv2 = xs[n][tt * 5 + 2];
            float xv3 = xs[n][tt * 5 + 3];
            float xv4 = xs[n][tt * 5 + 4];
#pragma unroll
            for (int i = 0; i < 8; i++) {
                acc[i][0] += qa[i] * xv0;
                acc[i][1] += qa[i] * xv1;
                acc[i][2] += qa[i] * xv2;
                acc[i][3] += qa[i] * xv3;
                acc[i][4] += qa[i] * xv4;
            }
        }
#pragma unroll
        for (int i = 0; i < 8; i++) {
            float pm = -1e30f, nm = -1e30f;
#pragma unroll
            for (int j = 0; j < 5; j++) {
                float s = acc[i][j] * rnorm[tt * 5 + j];
                pm = fmaxf(pm, s);
                nm = fmaxf(nm, -s);
            }
            poolp[pt * 8 + i][tt] = pm;
            pooln[pt * 8 + i][tt] = nm;
        }
    }
    __syncthreads();

    float rsap = 1.0f / (float)(length[b] / STRIDE_);
    for (int p = threadIdx.x; p < P_; p += 256) {
        float pm = poolp[p][0], nm = pooln[p][0];
#pragma unroll
        for (int q = 1; q < 5; q++) {
            pm = fmaxf(pm, poolp[p][q]);
            nm = fmaxf(nm, pooln[p][q]);
        }
        atomicAdd(&pes[b * P_ + p], (pm + nm) * 0.5f * rsap);
    }
}

__global__ __launch_bounds__(256) void fb_graphs_kernel(const float* __restrict__ ws,
                                                        float* __restrict__ out) {
    int idx = blockIdx.x * 256 + threadIdx.x;
    if (idx == 0) {
        out[(size_t)B_ * N_ * N_] = ws[OFF_NORM];
        out[(size_t)B_ * N_ * N_ + 1] = ws[OFF_ORTH];
    }
    if (idx >= B_ * P_) return;
    int b = idx / P_;
    int p = idx - b * P_;
    float e = ws[OFF_PES + b * P_ + p];
    const float* keyval = ws + OFF_KEYVAL;
    const int* keyidx = (const int*)(ws + OFF_KEYIDX);
    float va[3] = { keyval[p * 4 + 0], keyval[p * 4 + 1], keyval[p * 4 + 2] };
    int ia[3] = { keyidx[p * 4 + 0], keyidx[p * 4 + 1], keyidx[p * 4 + 2] };
    float* g = out + (size_t)b * N_ * N_;
#pragma unroll
    for (int a = 0; a < 3; a++)
#pragma unroll
        for (int c = 0; c < 3; c++) {
            float scale = (ia[a] == ia[c]) ? 1.0f : 6.0f;
            atomicAdd(&g[ia[a] * N_ + ia[c]], va[a] * va[c] * e * scale);
        }
}

__global__ __launch_bounds__(64) void pat_kernel(const float* __restrict__ patterns,
                                                 float* __restrict__ ws) {
    float d2 = pat_body(patterns, ws, blockIdx.x, threadIdx.x & 63);
    if (threadIdx.x == 0) atomicAdd(ws + OFF_NORM, d2);
}
__global__ __launch_bounds__(256) void orth_kernel(float* __restrict__ ws) {
    __shared__ float rowi[N_];
    __shared__ float red[256];
    const float* npatT = ws + OFF_NPATT;
    int i = blockIdx.x;
    for (int k = threadIdx.x; k < N_; k += 256) rowi[k] = npatT[k * P_ + i];
    __syncthreads();
    float partial = 0.0f;
    for (int j = threadIdx.x; j < P_; j += 256) {
        if (j == i) continue;
        float s = 0.0f;
        for (int k = 0; k < N_; k++) s += rowi[k] * npatT[k * P_ + j];
        float t = (fabsf(s) - 0.3f) * (1.0f / 0.70001f);
        if (t > 0.0f) partial += t * t;
    }
    red[threadIdx.x] = partial;
    __syncthreads();
    for (int sft = 128; sft; sft >>= 1) {
        if (threadIdx.x < sft) red[threadIdx.x] += red[threadIdx.x + sft];
        __syncthreads();
    }
    if (threadIdx.x == 0)
        atomicAdd(ws + OFF_ORTH, red[0] * (1.0f / ((float)P_ * (float)P_)));
}

extern "C" void kernel_launch(void* const* d_in, const int* in_sizes, int n_in,
                              void* d_out, int out_size, void* d_ws, size_t ws_size,
                              hipStream_t stream) {
    const float* x = (const float*)d_in[0];
    const float* patterns = (const float*)d_in[1];
    const int* length = (const int*)d_in[2];
    float* out = (float*)d_out;
    float* ws = (float*)d_ws;

    if (ws_size >= (size_t)WS_FAST_FLOATS * sizeof(float)) {
        unsigned* gpool = (unsigned*)(ws + OFF_GPOOL);
        prep_kernel<<<PREP_BLKS, 256, 0, stream>>>(x, patterns, ws);
        work_kernel<<<660, 256, 0, stream>>>(ws, gpool);
        graphs_row_kernel<<<B_ * 4, 256, 0, stream>>>(gpool, length, ws, out);
    } else {
        (void)hipMemsetAsync(d_out, 0, (size_t)B_ * N_ * N_ * sizeof(float), stream);
        (void)hipMemsetAsync(ws + OFF_PES, 0, (size_t)(B_ * P_) * sizeof(float), stream);
        (void)hipMemsetAsync(ws + OFF_NORM, 0, sizeof(float), stream);
        (void)hipMemsetAsync(ws + OFF_ORTH, 0, sizeof(float), stream);
        pat_kernel<<<P_, 64, 0, stream>>>(patterns, ws);
        orth_kernel<<<P_, 256, 0, stream>>>(ws);
        main_kernel<<<dim3(T_ / STRIDE_, B_), 256, 0, stream>>>(x, length, ws, ws + OFF_PES);
        fb_graphs_kernel<<<(B_ * P_ + 255) / 256, 256, 0, stream>>>(ws, out);
    }
}

// Round 18
// 68.912 us; speedup vs baseline: 1.0153x; 1.0153x over previous
//
#include <hip/hip_runtime.h>
#include <math.h>

#define B_ 64
#define N_ 200
#define P_ 400
#define T_ 1200
#define TPAD 1280
#define PPAD 512
#define STRIDE_ 25
#define EPS_ 1e-9f
#define KPAD 224

// ws layout (float offsets)
#define OFF_NPATT  0            // [N_][P_] f32 (fallback orth path)
#define OFF_NPB16  80000        // [P_][KPAD] bf16 row-major patterns
#define OFF_KEYVAL 124800       // [P_][4]
#define OFF_KEYIDX 126400       // [P_][4] int
#define OFF_PES    128000       // [B_][P_] (fallback only)
#define OFF_NORMB  153600       // [100] per-pat-block norm partials
#define OFF_ORTHB  153700       // [20] per-orth-block partials
#define OFF_NORM   OFF_NORMB    // fallback scalar slot
#define OFF_ORTH   OFF_ORTHB
#define OFF_NPBT   153728       // [28][PPAD][8] bf16 K-outer patterns (57344 f32)
#define OFF_XN     211072       // [B_][28][TPAD][8] bf16 K-outer frames (9175040 f32)
#define OFF_GPOOL  9386112      // [2][B_][10mb][7][400] okey uints (3,584,000)
#define WS_FAST_FLOATS (9386112 + 3584000)

// prep block roles
#define ZP_BLKS  2              // zero npbT pad rows
#define PAT_BLKS 100
#define TN_BLKS  (20 * B_)      // 1280
#define Z_ALL    ZP_BLKS
#define PREP_BLKS (Z_ALL + PAT_BLKS + TN_BLKS)

// work grid: 1600 gemm (5pb x 5mbg x 64b, 2 mb-tiles each) + 20 orth
#define GEMM_BLKS 1600
#define WORK_BLKS 1620

typedef float f4v __attribute__((ext_vector_type(4)));
typedef short s8v __attribute__((ext_vector_type(8)));

__device__ inline unsigned short f2bf(float f) {
    union { float f; unsigned u; } v; v.f = f;
    unsigned r = v.u + 0x7FFFu + ((v.u >> 16) & 1u);
    return (unsigned short)(r >> 16);
}
__device__ inline unsigned okey(float f) {
    unsigned u = __float_as_uint(f);
    return (u & 0x80000000u) ? ~u : (u | 0x80000000u);
}
__device__ inline float dekey(unsigned k) {
    unsigned u = (k & 0x80000000u) ? (k & 0x7fffffffu) : ~k;
    return __uint_as_float(u);
}

// ======= pat body (one wave, one pattern). Returns lane0's norm term. =======
__device__ float pat_body(const float* __restrict__ patterns, float* __restrict__ ws,
                          int p, int lane) {
    float v0 = patterns[p * N_ + lane];
    float v1 = patterns[p * N_ + lane + 64];
    float v2 = patterns[p * N_ + lane + 128];
    float v3 = (lane < 8) ? patterns[p * N_ + lane + 192] : 0.0f;

    float ss = v0 * v0 + v1 * v1 + v2 * v2 + v3 * v3;
    for (int off = 32; off; off >>= 1) ss += __shfl_down(ss, off);
    ss = __shfl(ss, 0);

    float rn = 1.0f / sqrtf(ss + EPS_);
    float s0 = v0 * rn, s1 = v1 * rn, s2 = v2 * rn, s3 = v3 * rn;

    float* npatT = ws + OFF_NPATT;
    npatT[(lane) * P_ + p] = s0;
    npatT[(lane + 64) * P_ + p] = s1;
    npatT[(lane + 128) * P_ + p] = s2;
    if (lane < 8) npatT[(lane + 192) * P_ + p] = s3;

    unsigned short* npb = (unsigned short*)(ws + OFF_NPB16);
    unsigned short b0 = f2bf(s0), b1 = f2bf(s1), b2 = f2bf(s2), b3 = f2bf(s3);
    npb[p * KPAD + lane] = b0;
    npb[p * KPAD + lane + 64] = b1;
    npb[p * KPAD + lane + 128] = b2;
    if (lane < 8) npb[p * KPAD + lane + 192] = b3;
    if (lane < 24) npb[p * KPAD + 200 + lane] = 0;

    unsigned short* npbT = (unsigned short*)(ws + OFF_NPBT);
    {
        int k0 = lane, k1 = lane + 64, k2 = lane + 128;
        npbT[(k0 >> 3) * (PPAD * 8) + p * 8 + (k0 & 7)] = b0;
        npbT[(k1 >> 3) * (PPAD * 8) + p * 8 + (k1 & 7)] = b1;
        npbT[(k2 >> 3) * (PPAD * 8) + p * 8 + (k2 & 7)] = b2;
        if (lane < 8) {
            int k3 = lane + 192;
            npbT[(k3 >> 3) * (PPAD * 8) + p * 8 + (k3 & 7)] = b3;
        }
        if (lane < 24) {
            int k4 = 200 + lane;
            npbT[(k4 >> 3) * (PPAD * 8) + p * 8 + (k4 & 7)] = 0;
        }
    }

    float a0 = fabsf(s0), a1 = fabsf(s1), a2 = fabsf(s2), a3 = fabsf(s3);

    int ch0 = -1, ch1 = -1, ch2 = -1;
    float cs0 = 0.f, cs1 = 0.f, cs2 = 0.f;

    for (int r = 0; r < 3; r++) {
        float bv = -1.0f;
        int bi = 1 << 30;
        {
            int n = lane;
            bool sk = (n == ch0) || (n == ch1) || (n == ch2);
            if (!sk && a0 > bv) { bv = a0; bi = n; }
        }
        {
            int n = lane + 64;
            bool sk = (n == ch0) || (n == ch1) || (n == ch2);
            if (!sk && (a1 > bv || (a1 == bv && n < bi))) { bv = a1; bi = n; }
        }
        {
            int n = lane + 128;
            bool sk = (n == ch0) || (n == ch1) || (n == ch2);
            if (!sk && (a2 > bv || (a2 == bv && n < bi))) { bv = a2; bi = n; }
        }
        if (lane < 8) {
            int n = lane + 192;
            bool sk = (n == ch0) || (n == ch1) || (n == ch2);
            if (!sk && (a3 > bv || (a3 == bv && n < bi))) { bv = a3; bi = n; }
        }
        for (int off = 32; off; off >>= 1) {
            float ov = __shfl_down(bv, off);
            int oi = __shfl_down(bi, off);
            if (ov > bv || (ov == bv && oi < bi)) { bv = ov; bi = oi; }
        }
        bi = __shfl(bi, 0);
        int slot = bi >> 6, src = bi & 63;
        float mine = (slot == 0) ? s0 : (slot == 1) ? s1 : (slot == 2) ? s2 : s3;
        float sval = __shfl(mine, src);
        if (r == 0) { ch0 = bi; cs0 = sval; }
        else if (r == 1) { ch1 = bi; cs1 = sval; }
        else { ch2 = bi; cs2 = sval; }
    }

    float d2 = 0.f;
    if (lane == 0) {
        float* keyval = ws + OFF_KEYVAL;
        int* keyidx = (int*)(ws + OFF_KEYIDX);
        keyval[p * 4 + 0] = cs0; keyval[p * 4 + 1] = cs1; keyval[p * 4 + 2] = cs2;
        keyval[p * 4 + 3] = 0.f;
        keyidx[p * 4 + 0] = ch0; keyidx[p * 4 + 1] = ch1; keyidx[p * 4 + 2] = ch2;
        keyidx[p * 4 + 3] = -1;
        float lenp = sqrtf(ss) * rn;
        float lentopp = sqrtf(cs0 * cs0 + cs1 * cs1 + cs2 * cs2);
        float d = 1.0f - lentopp / lenp;
        d2 = d * d * (1.0f / (float)P_);
    }
    return d2;
}

// == prep: zero npbT-pad (0..1) + pat (2..101) + tnorm (102..1381) ===========
__global__ __launch_bounds__(256) void prep_kernel(const float* __restrict__ x,
                                                   const float* __restrict__ patterns,
                                                   float* __restrict__ ws) {
    __shared__ unsigned short xt16[64 * 210];
    __shared__ float psums[256];
    __shared__ float rns[64];
    __shared__ float sh4[4];

    const int tid = threadIdx.x;

    if (blockIdx.x < Z_ALL) {
        unsigned* p32 = (unsigned*)(ws + OFF_NPBT);
        int lb = blockIdx.x;
        for (int e = lb * 256 + tid; e < 12544; e += ZP_BLKS * 256) {
            int seg = e / 448, r32 = e % 448;
            p32[seg * 2048 + 1600 + r32] = 0u;
        }
        return;
    }

    if (blockIdx.x < Z_ALL + PAT_BLKS) {
        int pblk = blockIdx.x - Z_ALL;
        int wv = tid >> 6, lane = tid & 63;
        int p = pblk * 4 + wv;
        float d2 = pat_body(patterns, ws, p, lane);
        if (lane == 0) sh4[wv] = d2;
        __syncthreads();
        if (tid == 0)
            ws[OFF_NORMB + pblk] = sh4[0] + sh4[1] + sh4[2] + sh4[3];
        return;
    }

    const int blk = blockIdx.x - Z_ALL - PAT_BLKS;
    const int t = tid & 63, r = tid >> 6;
    const int b = blk / 20;
    const int t0 = (blk % 20) * 64;
    const bool valid = (t0 + t) < T_;

    float ss = 0.0f;
    if (valid) {
        const float* xp = x + (size_t)b * N_ * T_ + t0 + t;
#pragma unroll 5
        for (int i = 0; i < 50; ++i) {
            int n = r * 50 + i;
            float v = xp[(size_t)n * T_];
            ss += v * v;
            xt16[t * 210 + n] = f2bf(v);
        }
    }
    psums[tid] = ss;
    __syncthreads();
    if (tid < 64) {
        float s = psums[tid] + psums[tid + 64] + psums[tid + 128] + psums[tid + 192];
        rns[tid] = rsqrtf(s + EPS_);
    }
    __syncthreads();

    unsigned short* xnT = (unsigned short*)(ws + OFF_XN);
#pragma unroll
    for (int j = 0; j < 7; ++j) {
        int idx = tid + 256 * j;
        int seg = idx >> 6, tt = idx & 63;
        s8v ov = (s8v){0, 0, 0, 0, 0, 0, 0, 0};
        if (seg < 25 && (t0 + tt) < T_) {
            float rn = rns[tt];
            const unsigned* src = (const unsigned*)&xt16[tt * 210 + seg * 8];
            unsigned o[4];
#pragma unroll
            for (int i = 0; i < 4; ++i) {
                unsigned u = src[i];
                float lo = __uint_as_float(u << 16) * rn;
                float hi = __uint_as_float(u & 0xffff0000u) * rn;
                o[i] = (unsigned)f2bf(lo) | ((unsigned)f2bf(hi) << 16);
            }
            ov = (s8v){(short)(o[0] & 0xffff), (short)(o[0] >> 16),
                       (short)(o[1] & 0xffff), (short)(o[1] >> 16),
                       (short)(o[2] & 0xffff), (short)(o[2] >> 16),
                       (short)(o[3] & 0xffff), (short)(o[3] >> 16)};
        }
        *(s8v*)(xnT + (((size_t)b * 28 + seg) * TPAD + t0 + tt) * 8) = ov;
    }
}

// ======= work: gemm (nid 0..1599, 2 mb-tiles each) + orth (1600..1619) ======
// ldsB [80][224] bf16 XOR-swizzled -> 40.3 KB total LDS -> 4 blocks/CU.
__global__ __launch_bounds__(256, 4) void work_kernel(float* __restrict__ ws,
                                                      unsigned* __restrict__ gpool) {
    __shared__ short ldsB[80 * 224];           // 35.84 KB
    __shared__ unsigned pool[2 * 7 * 80];      // 4.48 KB

    const int tid = threadIdx.x;
    const unsigned OKNEG = okey(-1e30f);
    // bijective XCD swizzle over 1620 blocks: q=202, r=4 (xcd<4 get 203)
    int orig = blockIdx.x;
    int xcd = orig & 7, rem = orig >> 3;
    int nid = (xcd < 4 ? xcd * 203 : 4 * 203 + (xcd - 4) * 202) + rem;

    const bool isOrth = (nid >= GEMM_BLKS);
    int pb, mbg, b;
    if (isOrth) { int o = nid - GEMM_BLKS; pb = o % 5; mbg = o / 5; b = 0; }
    else        { pb = nid % 5; mbg = (nid / 5) % 5; b = nid / 25; }

    const unsigned short* npb = (const unsigned short*)(ws + OFF_NPB16) + (size_t)(pb * 80) * KPAD;

    // stage B once (swizzled): 80 rows x 28 16B-units
#pragma unroll
    for (int j = 0; j < 9; ++j) {
        int idx = tid + 256 * j;
        if (idx < 2240) {
            int row = idx / 28, seg = idx % 28;
            int off = row * 224 + ((seg * 8) ^ ((row & 3) << 3));
            *(s8v*)(&ldsB[off]) = *(const s8v*)(npb + (size_t)row * KPAD + seg * 8);
        }
    }
    for (int i = tid; i < 1120; i += 256) pool[i] = OKNEG;
    __syncthreads();

    const int wv = tid >> 6;
    const int lane = tid & 63;
    const int l15 = lane & 15, kg = lane >> 4;
    const int bswz = (l15 & 3) << 3;

    const int ROWS = isOrth ? PPAD : TPAD;
    const unsigned short* abase = isOrth
        ? (const unsigned short*)(ws + OFF_NPBT)
        : (const unsigned short*)(ws + OFF_XN) + (size_t)b * 28 * TPAD * 8;
    const int segstep = 4 * ROWS * 8;
    const int niter = isOrth ? 1 : 2;

    float orthpart = 0.f;

    for (int it = 0; it < niter; ++it) {
        const int mb = isOrth ? mbg : (mbg * 2 + it);
        const int row0 = mb * 128 + wv * 32 + l15;
        const unsigned short* ar0 = abase + ((size_t)kg * ROWS + row0) * 8;
        const unsigned short* ar1 = ar0 + 16 * 8;

        f4v acc[2][5];
#pragma unroll
        for (int mi = 0; mi < 2; ++mi)
#pragma unroll
            for (int ni = 0; ni < 5; ++ni) acc[mi][ni] = (f4v){0.f, 0.f, 0.f, 0.f};

        s8v A[4][2];
#pragma unroll
        for (int c = 0; c < 4; ++c) {
            A[c][0] = *(const s8v*)(ar0 + c * segstep);
            A[c][1] = *(const s8v*)(ar1 + c * segstep);
        }

#pragma unroll
        for (int c = 0; c < 7; ++c) {
            if (c + 4 < 7) {
                A[(c + 4) & 3][0] = *(const s8v*)(ar0 + (c + 4) * segstep);
                A[(c + 4) & 3][1] = *(const s8v*)(ar1 + (c + 4) * segstep);
            }
            s8v bf[5];
#pragma unroll
            for (int ni = 0; ni < 5; ++ni)
                bf[ni] = *(const s8v*)(&ldsB[(ni * 16 + l15) * 224 + ((c * 32 + kg * 8) ^ bswz)]);
#pragma unroll
            for (int ni = 0; ni < 5; ++ni) {
                acc[0][ni] = __builtin_amdgcn_mfma_f32_16x16x32_bf16(A[c & 3][0], bf[ni], acc[0][ni], 0, 0, 0);
                acc[1][ni] = __builtin_amdgcn_mfma_f32_16x16x32_bf16(A[c & 3][1], bf[ni], acc[1][ni], 0, 0, 0);
            }
        }

        if (isOrth) {
#pragma unroll
            for (int mi = 0; mi < 2; ++mi) {
                int rb = mb * 128 + wv * 32 + mi * 16 + kg * 4;
#pragma unroll
                for (int ni = 0; ni < 5; ++ni) {
                    int col = pb * 80 + ni * 16 + l15;
#pragma unroll
                    for (int jj = 0; jj < 4; ++jj) {
                        if (rb + jj == col) continue;
                        float t = (fabsf(acc[mi][ni][jj]) - 0.3f) * (1.0f / 0.70001f);
                        if (t > 0.0f) orthpart += t * t;
                    }
                }
            }
            break;
        }

        const int wbase = (mb * 128) / 25;
#pragma unroll
        for (int mi = 0; mi < 2; ++mi) {
            int f0 = mb * 128 + wv * 32 + mi * 16 + kg * 4;
            int w0 = f0 / 25, w3 = (f0 + 3) / 25;
            int wsplit = w3 * 25;
#pragma unroll
            for (int ni = 0; ni < 5; ++ni) {
                int pc = ni * 16 + l15;
                float p0 = -1e30f, p1 = -1e30f, n0 = -1e30f, n1 = -1e30f;
#pragma unroll
                for (int jj = 0; jj < 4; ++jj) {
                    float v = acc[mi][ni][jj];
                    if (f0 + jj < wsplit) { p0 = fmaxf(p0, v); n0 = fmaxf(n0, -v); }
                    else                 { p1 = fmaxf(p1, v); n1 = fmaxf(n1, -v); }
                }
                atomicMax(&pool[(0 * 7 + (w3 - wbase)) * 80 + pc], okey(p1));
                atomicMax(&pool[(1 * 7 + (w3 - wbase)) * 80 + pc], okey(n1));
                if (w0 != w3) {
                    atomicMax(&pool[(0 * 7 + (w0 - wbase)) * 80 + pc], okey(p0));
                    atomicMax(&pool[(1 * 7 + (w0 - wbase)) * 80 + pc], okey(n0));
                }
            }
        }
        __syncthreads();
        for (int e = tid; e < 1120; e += 256) {
            int pass = e / 560, r2 = e % 560;
            int slot = r2 / 80, pp = r2 % 80;
            gpool[(((size_t)(pass * B_ + b)) * 10 + mb) * 2800 + slot * 400 + pb * 80 + pp] = pool[e];
            pool[e] = OKNEG;
        }
        __syncthreads();
    }

    if (isOrth) {
        for (int off = 32; off; off >>= 1) orthpart += __shfl_down(orthpart, off);
        __syncthreads();
        float* red = (float*)pool;
        if (lane == 0) red[wv] = orthpart;
        __syncthreads();
        if (tid == 0)
            ws[OFF_ORTHB + (nid - GEMM_BLKS)] = (red[0] + red[1] + red[2] + red[3]) *
                                                (1.0f / ((float)P_ * (float)P_));
    }
}

// ======= graphs_row: PES merge + row-gather + NT stream =====================
__global__ __launch_bounds__(256) void graphs_row_kernel(const unsigned* __restrict__ gpool,
                                                         const int* __restrict__ length,
                                                         const float* __restrict__ ws,
                                                         float* __restrict__ out) {
    __shared__ float rowbuf[50 * 200];
    __shared__ int   ki[400][4];
    __shared__ float kv[400][4];
    __shared__ float el[400];

    const int tid = threadIdx.x;
    const int b = blockIdx.x >> 2;
    const int n0 = (blockIdx.x & 3) * 50;

    for (int i = tid; i < 10000; i += 256) rowbuf[i] = 0.f;
    for (int p = tid; p < 400; p += 256) {
        *(int4*)ki[p] = ((const int4*)(ws + OFF_KEYIDX))[p];
        *(float4*)kv[p] = ((const float4*)(ws + OFF_KEYVAL))[p];
    }

    float rsap = 1.0f / (float)(length[b] / STRIDE_);
    for (int p = tid; p < 400; p += 256) {
        float s = 0.f;
#pragma unroll
        for (int pass = 0; pass < 2; ++pass) {
            const unsigned* gp = gpool + ((size_t)(pass * B_ + b)) * 10 * 2800 + p;
            unsigned v[10][7];
#pragma unroll
            for (int mb = 0; mb < 10; ++mb)
#pragma unroll
                for (int sl = 0; sl < 7; ++sl)
                    v[mb][sl] = gp[mb * 2800 + sl * 400];
#pragma unroll
            for (int w = 0; w < 48; ++w) {
                int a = 25 * w - 127;
                int mb_lo = (a <= 0) ? 0 : ((a + 127) >> 7);
                int mb_hi = (25 * w + 24) >> 7;
                if (mb_hi > 9) mb_hi = 9;
                unsigned k = 0u;
#pragma unroll
                for (int mb = 0; mb < 10; ++mb) {
                    if (mb < mb_lo || mb > mb_hi) continue;
                    int slot = w - (mb * 128) / 25;
                    unsigned vv = v[mb][slot];
                    k = (vv > k) ? vv : k;
                }
                s += dekey(k);
            }
        }
        el[p] = s * 0.5f * rsap;
    }
    __syncthreads();

    for (int p = tid; p < 400; p += 256) {
        float e = el[p];
#pragma unroll
        for (int a = 0; a < 3; ++a) {
            int n = ki[p][a];
            if (n < n0 || n >= n0 + 50) continue;
            float va = kv[p][a] * e;
#pragma unroll
            for (int c = 0; c < 3; ++c) {
                float scale = (a == c) ? 1.0f : 6.0f;
                atomicAdd(&rowbuf[(n - n0) * 200 + ki[p][c]], va * kv[p][c] * scale);
            }
        }
    }
    __syncthreads();

    f4v* dst = (f4v*)(out + (size_t)b * N_ * N_ + (size_t)n0 * N_);
    const f4v* srcb = (const f4v*)rowbuf;
    for (int i = tid; i < 2500; i += 256)
        __builtin_nontemporal_store(srcb[i], dst + i);

    if (blockIdx.x == 0 && tid == 0) {
        float sn = 0.f;
        for (int i = 0; i < PAT_BLKS; ++i) sn += ws[OFF_NORMB + i];
        float so = 0.f;
        for (int i = 0; i < 20; ++i) so += ws[OFF_ORTHB + i];
        out[(size_t)B_ * N_ * N_] = sn;
        out[(size_t)B_ * N_ * N_ + 1] = so;
    }
}

// ---------------- fallback path (fp32, ws-size independent) -----------------
__global__ __launch_bounds__(256) void main_kernel(const float* __restrict__ x,
                                                   const int* __restrict__ length,
                                                   const float* __restrict__ ws,
                                                   float* __restrict__ pes) {
    __shared__ float xs[N_][STRIDE_ + 1];
    __shared__ float rnorm[STRIDE_];
    __shared__ float poolp[P_][5];
    __shared__ float pooln[P_][5];

    int w = blockIdx.x;
    int b = blockIdx.y;
    const float* xb = x + (size_t)b * N_ * T_ + (size_t)w * STRIDE_;

    for (int i = threadIdx.x; i < N_ * STRIDE_; i += 256) {
        int n = i / STRIDE_;
        int t = i - n * STRIDE_;
        xs[n][t] = xb[n * T_ + t];
    }
    __syncthreads();

    if (threadIdx.x < STRIDE_) {
        float ssf = 0.0f;
        for (int n = 0; n < N_; n++) { float vv = xs[n][threadIdx.x]; ssf += vv * vv; }
        rnorm[threadIdx.x] = 1.0f / sqrtf(ssf + EPS_);
    }
    __syncthreads();

    int pt = threadIdx.x % 50;
    int tt = threadIdx.x / 50;

    if (tt < 5) {
        float acc[8][5];
#pragma unroll
        for (int i = 0; i < 8; i++)
#pragma unroll
            for (int j = 0; j < 5; j++) acc[i][j] = 0.0f;

        const float4* np4 = (const float4*)(ws + OFF_NPATT);
        int pbq = pt * 2;
        for (int n = 0; n < N_; n++) {
            float4 q0 = np4[n * (P_ / 4) + pbq];
            float4 q1 = np4[n * (P_ / 4) + pbq + 1];
            float qa[8] = { q0.x, q0.y, q0.z, q0.w, q1.x, q1.y, q1.z, q1.w };
            float xv0 = xs[n][tt * 5 + 0];
            float xv1 = xs[n][tt * 5 + 1];
            float xv2 = xs[n][tt * 5 + 2];
            float xv3 = xs[n][tt * 5 + 3];
            float xv4 = xs[n][tt * 5 + 4];
#pragma unroll
            for (int i = 0; i < 8; i++) {
                acc[i][0] += qa[i] * xv0;
                acc[i][1] += qa[i] * xv1;
                acc[i][2] += qa[i] * xv2;
                acc[i][3] += qa[i] * xv3;
                acc[i][4] += qa[i] * xv4;
            }
        }
#pragma unroll
        for (int i = 0; i < 8; i++) {
            float pm = -1e30f, nm = -1e30f;
#pragma unroll
            for (int j = 0; j < 5; j++) {
                float s = acc[i][j] * rnorm[tt * 5 + j];
                pm = fmaxf(pm, s);
                nm = fmaxf(nm, -s);
            }
            poolp[pt * 8 + i][tt] = pm;
            pooln[pt * 8 + i][tt] = nm;
        }
    }
    __syncthreads();

    float rsap = 1.0f / (float)(length[b] / STRIDE_);
    for (int p = threadIdx.x; p < P_; p += 256) {
        float pm = poolp[p][0], nm = pooln[p][0];
#pragma unroll
        for (int q = 1; q < 5; q++) {
            pm = fmaxf(pm, poolp[p][q]);
            nm = fmaxf(nm, pooln[p][q]);
        }
        atomicAdd(&pes[b * P_ + p], (pm + nm) * 0.5f * rsap);
    }
}

__global__ __launch_bounds__(256) void fb_graphs_kernel(const float* __restrict__ ws,
                                                        float* __restrict__ out) {
    int idx = blockIdx.x * 256 + threadIdx.x;
    if (idx == 0) {
        out[(size_t)B_ * N_ * N_] = ws[OFF_NORM];
        out[(size_t)B_ * N_ * N_ + 1] = ws[OFF_ORTH];
    }
    if (idx >= B_ * P_) return;
    int b = idx / P_;
    int p = idx - b * P_;
    float e = ws[OFF_PES + b * P_ + p];
    const float* keyval = ws + OFF_KEYVAL;
    const int* keyidx = (const int*)(ws + OFF_KEYIDX);
    float va[3] = { keyval[p * 4 + 0], keyval[p * 4 + 1], keyval[p * 4 + 2] };
    int ia[3] = { keyidx[p * 4 + 0], keyidx[p * 4 + 1], keyidx[p * 4 + 2] };
    float* g = out + (size_t)b * N_ * N_;
#pragma unroll
    for (int a = 0; a < 3; a++)
#pragma unroll
        for (int c = 0; c < 3; c++) {
            float scale = (ia[a] == ia[c]) ? 1.0f : 6.0f;
            atomicAdd(&g[ia[a] * N_ + ia[c]], va[a] * va[c] * e * scale);
        }
}

__global__ __launch_bounds__(64) void pat_kernel(const float* __restrict__ patterns,
                                                 float* __restrict__ ws) {
    float d2 = pat_body(patterns, ws, blockIdx.x, threadIdx.x & 63);
    if (threadIdx.x == 0) atomicAdd(ws + OFF_NORM, d2);
}
__global__ __launch_bounds__(256) void orth_kernel(float* __restrict__ ws) {
    __shared__ float rowi[N_];
    __shared__ float red[256];
    const float* npatT = ws + OFF_NPATT;
    int i = blockIdx.x;
    for (int k = threadIdx.x; k < N_; k += 256) rowi[k] = npatT[k * P_ + i];
    __syncthreads();
    float partial = 0.0f;
    for (int j = threadIdx.x; j < P_; j += 256) {
        if (j == i) continue;
        float s = 0.0f;
        for (int k = 0; k < N_; k++) s += rowi[k] * npatT[k * P_ + j];
        float t = (fabsf(s) - 0.3f) * (1.0f / 0.70001f);
        if (t > 0.0f) partial += t * t;
    }
    red[threadIdx.x] = partial;
    __syncthreads();
    for (int sft = 128; sft; sft >>= 1) {
        if (threadIdx.x < sft) red[threadIdx.x] += red[threadIdx.x + sft];
        __syncthreads();
    }
    if (threadIdx.x == 0)
        atomicAdd(ws + OFF_ORTH, red[0] * (1.0f / ((float)P_ * (float)P_)));
}

extern "C" void kernel_launch(void* const* d_in, const int* in_sizes, int n_in,
                              void* d_out, int out_size, void* d_ws, size_t ws_size,
                              hipStream_t stream) {
    const float* x = (const float*)d_in[0];
    const float* patterns = (const float*)d_in[1];
    const int* length = (const int*)d_in[2];
    float* out = (float*)d_out;
    float* ws = (float*)d_ws;

    if (ws_size >= (size_t)WS_FAST_FLOATS * sizeof(float)) {
        unsigned* gpool = (unsigned*)(ws + OFF_GPOOL);
        prep_kernel<<<PREP_BLKS, 256, 0, stream>>>(x, patterns, ws);
        work_kernel<<<WORK_BLKS, 256, 0, stream>>>(ws, gpool);
        graphs_row_kernel<<<B_ * 4, 256, 0, stream>>>(gpool, length, ws, out);
    } else {
        (void)hipMemsetAsync(d_out, 0, (size_t)B_ * N_ * N_ * sizeof(float), stream);
        (void)hipMemsetAsync(ws + OFF_PES, 0, (size_t)(B_ * P_) * sizeof(float), stream);
        (void)hipMemsetAsync(ws + OFF_NORM, 0, sizeof(float), stream);
        (void)hipMemsetAsync(ws + OFF_ORTH, 0, sizeof(float), stream);
        pat_kernel<<<P_, 64, 0, stream>>>(patterns, ws);
        orth_kernel<<<P_, 256, 0, stream>>>(ws);
        main_kernel<<<dim3(T_ / STRIDE_, B_), 256, 0, stream>>>(x, length, ws, ws + OFF_PES);
        fb_graphs_kernel<<<(B_ * P_ + 255) / 256, 256, 0, stream>>>(ws, out);
    }
}

// Round 19
// 66.822 us; speedup vs baseline: 1.0471x; 1.0313x over previous
//
#include <hip/hip_runtime.h>
#include <math.h>

#define B_ 64
#define N_ 200
#define P_ 400
#define T_ 1200
#define TPAD 1280
#define PPAD 512
#define STRIDE_ 25
#define EPS_ 1e-9f
#define KPAD 224
#define BSTRIDE 232   // LDS B row stride in shorts (464B row: 2-way max, free)

// ws layout (float offsets)
#define OFF_NPATT  0            // [N_][P_] f32 (fallback orth path)
#define OFF_NPB16  80000        // [P_][KPAD] bf16 row-major patterns
#define OFF_KEYVAL 124800       // [P_][4]
#define OFF_KEYIDX 126400       // [P_][4] int
#define OFF_PES    128000       // [B_][P_] PES (written once, no zero needed)
#define OFF_NORMB  153600       // [100] per-pat-block norm partials
#define OFF_ORTHB  153700       // [20] per-orth-block partials
#define OFF_NORM   OFF_NORMB    // fallback scalar slot
#define OFF_ORTH   OFF_ORTHB
#define OFF_NPBT   153728       // [28][PPAD][8] bf16 K-outer patterns (57344 f32)
#define OFF_XN     211072       // [B_][28][TPAD][8] bf16 K-outer frames (9175040 f32)
#define OFF_GPOOL  9386112      // [2][B_][10mb][7][400] okey uints (3,584,000)
#define WS_FAST_FLOATS (9386112 + 3584000)

// prep block roles
#define ZP_BLKS  2              // zero npbT pad rows
#define PAT_BLKS 100
#define TN_BLKS  (20 * B_)      // 1280
#define Z_ALL    ZP_BLKS
#define PREP_BLKS (Z_ALL + PAT_BLKS + TN_BLKS)

typedef float f4v __attribute__((ext_vector_type(4)));
typedef short s8v __attribute__((ext_vector_type(8)));

__device__ inline unsigned short f2bf(float f) {
    union { float f; unsigned u; } v; v.f = f;
    unsigned r = v.u + 0x7FFFu + ((v.u >> 16) & 1u);
    return (unsigned short)(r >> 16);
}
__device__ inline unsigned okey(float f) {
    unsigned u = __float_as_uint(f);
    return (u & 0x80000000u) ? ~u : (u | 0x80000000u);
}
__device__ inline float dekey(unsigned k) {
    unsigned u = (k & 0x80000000u) ? (k & 0x7fffffffu) : ~k;
    return __uint_as_float(u);
}

// ======= pat body (one wave, one pattern). Returns lane0's norm term. =======
__device__ float pat_body(const float* __restrict__ patterns, float* __restrict__ ws,
                          int p, int lane) {
    float v0 = patterns[p * N_ + lane];
    float v1 = patterns[p * N_ + lane + 64];
    float v2 = patterns[p * N_ + lane + 128];
    float v3 = (lane < 8) ? patterns[p * N_ + lane + 192] : 0.0f;

    float ss = v0 * v0 + v1 * v1 + v2 * v2 + v3 * v3;
    for (int off = 32; off; off >>= 1) ss += __shfl_down(ss, off);
    ss = __shfl(ss, 0);

    float rn = 1.0f / sqrtf(ss + EPS_);
    float s0 = v0 * rn, s1 = v1 * rn, s2 = v2 * rn, s3 = v3 * rn;

    float* npatT = ws + OFF_NPATT;
    npatT[(lane) * P_ + p] = s0;
    npatT[(lane + 64) * P_ + p] = s1;
    npatT[(lane + 128) * P_ + p] = s2;
    if (lane < 8) npatT[(lane + 192) * P_ + p] = s3;

    unsigned short* npb = (unsigned short*)(ws + OFF_NPB16);
    unsigned short b0 = f2bf(s0), b1 = f2bf(s1), b2 = f2bf(s2), b3 = f2bf(s3);
    npb[p * KPAD + lane] = b0;
    npb[p * KPAD + lane + 64] = b1;
    npb[p * KPAD + lane + 128] = b2;
    if (lane < 8) npb[p * KPAD + lane + 192] = b3;
    if (lane < 24) npb[p * KPAD + 200 + lane] = 0;

    unsigned short* npbT = (unsigned short*)(ws + OFF_NPBT);
    {
        int k0 = lane, k1 = lane + 64, k2 = lane + 128;
        npbT[(k0 >> 3) * (PPAD * 8) + p * 8 + (k0 & 7)] = b0;
        npbT[(k1 >> 3) * (PPAD * 8) + p * 8 + (k1 & 7)] = b1;
        npbT[(k2 >> 3) * (PPAD * 8) + p * 8 + (k2 & 7)] = b2;
        if (lane < 8) {
            int k3 = lane + 192;
            npbT[(k3 >> 3) * (PPAD * 8) + p * 8 + (k3 & 7)] = b3;
        }
        if (lane < 24) {
            int k4 = 200 + lane;
            npbT[(k4 >> 3) * (PPAD * 8) + p * 8 + (k4 & 7)] = 0;
        }
    }

    float a0 = fabsf(s0), a1 = fabsf(s1), a2 = fabsf(s2), a3 = fabsf(s3);

    int ch0 = -1, ch1 = -1, ch2 = -1;
    float cs0 = 0.f, cs1 = 0.f, cs2 = 0.f;

    for (int r = 0; r < 3; r++) {
        float bv = -1.0f;
        int bi = 1 << 30;
        {
            int n = lane;
            bool sk = (n == ch0) || (n == ch1) || (n == ch2);
            if (!sk && a0 > bv) { bv = a0; bi = n; }
        }
        {
            int n = lane + 64;
            bool sk = (n == ch0) || (n == ch1) || (n == ch2);
            if (!sk && (a1 > bv || (a1 == bv && n < bi))) { bv = a1; bi = n; }
        }
        {
            int n = lane + 128;
            bool sk = (n == ch0) || (n == ch1) || (n == ch2);
            if (!sk && (a2 > bv || (a2 == bv && n < bi))) { bv = a2; bi = n; }
        }
        if (lane < 8) {
            int n = lane + 192;
            bool sk = (n == ch0) || (n == ch1) || (n == ch2);
            if (!sk && (a3 > bv || (a3 == bv && n < bi))) { bv = a3; bi = n; }
        }
        for (int off = 32; off; off >>= 1) {
            float ov = __shfl_down(bv, off);
            int oi = __shfl_down(bi, off);
            if (ov > bv || (ov == bv && oi < bi)) { bv = ov; bi = oi; }
        }
        bi = __shfl(bi, 0);
        int slot = bi >> 6, src = bi & 63;
        float mine = (slot == 0) ? s0 : (slot == 1) ? s1 : (slot == 2) ? s2 : s3;
        float sval = __shfl(mine, src);
        if (r == 0) { ch0 = bi; cs0 = sval; }
        else if (r == 1) { ch1 = bi; cs1 = sval; }
        else { ch2 = bi; cs2 = sval; }
    }

    float d2 = 0.f;
    if (lane == 0) {
        float* keyval = ws + OFF_KEYVAL;
        int* keyidx = (int*)(ws + OFF_KEYIDX);
        keyval[p * 4 + 0] = cs0; keyval[p * 4 + 1] = cs1; keyval[p * 4 + 2] = cs2;
        keyval[p * 4 + 3] = 0.f;
        keyidx[p * 4 + 0] = ch0; keyidx[p * 4 + 1] = ch1; keyidx[p * 4 + 2] = ch2;
        keyidx[p * 4 + 3] = -1;
        float lenp = sqrtf(ss) * rn;
        float lentopp = sqrtf(cs0 * cs0 + cs1 * cs1 + cs2 * cs2);
        float d = 1.0f - lentopp / lenp;
        d2 = d * d * (1.0f / (float)P_);
    }
    return d2;
}

// == prep: zero npbT-pad (0..1) + pat (2..101) + tnorm (102..1381) ===========
__global__ __launch_bounds__(256) void prep_kernel(const float* __restrict__ x,
                                                   const float* __restrict__ patterns,
                                                   float* __restrict__ ws) {
    __shared__ unsigned short xt16[64 * 210];   // bf16 staging (26.9 KB)
    __shared__ float psums[256];
    __shared__ float rns[64];
    __shared__ float sh4[4];

    const int tid = threadIdx.x;

    if (blockIdx.x < Z_ALL) {
        unsigned* p32 = (unsigned*)(ws + OFF_NPBT);
        int lb = blockIdx.x;     // 0..1
        for (int e = lb * 256 + tid; e < 12544; e += ZP_BLKS * 256) {
            int seg = e / 448, r32 = e % 448;
            p32[seg * 2048 + 1600 + r32] = 0u;
        }
        return;
    }

    if (blockIdx.x < Z_ALL + PAT_BLKS) {
        int pblk = blockIdx.x - Z_ALL;
        int wv = tid >> 6, lane = tid & 63;
        int p = pblk * 4 + wv;
        float d2 = pat_body(patterns, ws, p, lane);
        if (lane == 0) sh4[wv] = d2;
        __syncthreads();
        if (tid == 0)
            ws[OFF_NORMB + pblk] = sh4[0] + sh4[1] + sh4[2] + sh4[3];
        return;
    }

    const int blk = blockIdx.x - Z_ALL - PAT_BLKS;
    const int t = tid & 63, r = tid >> 6;
    const int b = blk / 20;
    const int t0 = (blk % 20) * 64;
    const bool valid = (t0 + t) < T_;

    float ss = 0.0f;
    if (valid) {
        const float* xp = x + (size_t)b * N_ * T_ + t0 + t;
#pragma unroll 5
        for (int i = 0; i < 50; ++i) {
            int n = r * 50 + i;
            float v = xp[(size_t)n * T_];
            ss += v * v;
            xt16[t * 210 + n] = f2bf(v);
        }
    }
    psums[tid] = ss;
    __syncthreads();
    if (tid < 64) {
        float s = psums[tid] + psums[tid + 64] + psums[tid + 128] + psums[tid + 192];
        rns[tid] = rsqrtf(s + EPS_);
    }
    __syncthreads();

    unsigned short* xnT = (unsigned short*)(ws + OFF_XN);
#pragma unroll
    for (int j = 0; j < 7; ++j) {
        int idx = tid + 256 * j;
        int seg = idx >> 6, tt = idx & 63;
        s8v ov = (s8v){0, 0, 0, 0, 0, 0, 0, 0};
        if (seg < 25 && (t0 + tt) < T_) {
            float rn = rns[tt];
            const unsigned* src = (const unsigned*)&xt16[tt * 210 + seg * 8];
            unsigned o[4];
#pragma unroll
            for (int i = 0; i < 4; ++i) {
                unsigned u = src[i];
                float lo = __uint_as_float(u << 16) * rn;
                float hi = __uint_as_float(u & 0xffff0000u) * rn;
                o[i] = (unsigned)f2bf(lo) | ((unsigned)f2bf(hi) << 16);
            }
            ov = (s8v){(short)(o[0] & 0xffff), (short)(o[0] >> 16),
                       (short)(o[1] & 0xffff), (short)(o[1] >> 16),
                       (short)(o[2] & 0xffff), (short)(o[2] >> 16),
                       (short)(o[3] & 0xffff), (short)(o[3] >> 16)};
        }
        *(s8v*)(xnT + (((size_t)b * 28 + seg) * TPAD + t0 + tt) * 8) = ov;
    }
}

// ======= work: gemm (nid 0..639, 5 mb-tiles each) + orth (640..659) =========
__global__ __launch_bounds__(256, 4) void work_kernel(float* __restrict__ ws,
                                                      unsigned* __restrict__ gpool) {
    __shared__ short ldsB[80 * BSTRIDE];
    __shared__ unsigned pool[2 * 7 * 80];

    const int tid = threadIdx.x;
    const unsigned OKNEG = okey(-1e30f);
    int orig = blockIdx.x;
    int xcd = orig & 7, rem = orig >> 3;
    int nid = (xcd < 4 ? xcd * 83 : 4 * 83 + (xcd - 4) * 82) + rem;

    const bool isOrth = (nid >= 640);
    int pb, mbg, b;
    if (isOrth) { int o = nid - 640; pb = o % 5; mbg = o / 5; b = 0; }
    else        { pb = nid % 5; mbg = (nid / 5) % 2; b = nid / 10; }

    const unsigned short* npb = (const unsigned short*)(ws + OFF_NPB16) + (size_t)(pb * 80) * KPAD;

#pragma unroll
    for (int j = 0; j < 9; ++j) {
        int idx = tid + 256 * j;
        if (idx < 2240) {
            int row = idx / 28, seg = idx % 28;
            *(s8v*)(&ldsB[row * BSTRIDE + seg * 8]) = *(const s8v*)(npb + (size_t)row * KPAD + seg * 8);
        }
    }
    for (int i = tid; i < 1120; i += 256) pool[i] = OKNEG;
    __syncthreads();

    const int wv = tid >> 6;
    const int lane = tid & 63;
    const int l15 = lane & 15, kg = lane >> 4;

    const int ROWS = isOrth ? PPAD : TPAD;
    const unsigned short* abase = isOrth
        ? (const unsigned short*)(ws + OFF_NPBT)
        : (const unsigned short*)(ws + OFF_XN) + (size_t)b * 28 * TPAD * 8;
    const int segstep = 4 * ROWS * 8;
    const int niter = isOrth ? 1 : 5;

    float orthpart = 0.f;

    for (int it = 0; it < niter; ++it) {
        const int mb = isOrth ? mbg : (mbg * 5 + it);
        const int row0 = mb * 128 + wv * 32 + l15;
        const unsigned short* ar0 = abase + ((size_t)kg * ROWS + row0) * 8;
        const unsigned short* ar1 = ar0 + 16 * 8;

        f4v acc[2][5];
#pragma unroll
        for (int mi = 0; mi < 2; ++mi)
#pragma unroll
            for (int ni = 0; ni < 5; ++ni) acc[mi][ni] = (f4v){0.f, 0.f, 0.f, 0.f};

        s8v A[4][2];
#pragma unroll
        for (int c = 0; c < 4; ++c) {
            A[c][0] = *(const s8v*)(ar0 + c * segstep);
            A[c][1] = *(const s8v*)(ar1 + c * segstep);
        }

#pragma unroll
        for (int c = 0; c < 7; ++c) {
            if (c + 4 < 7) {
                A[(c + 4) & 3][0] = *(const s8v*)(ar0 + (c + 4) * segstep);
                A[(c + 4) & 3][1] = *(const s8v*)(ar1 + (c + 4) * segstep);
            }
            s8v bf[5];
#pragma unroll
            for (int ni = 0; ni < 5; ++ni)
                bf[ni] = *(const s8v*)(&ldsB[(ni * 16 + l15) * BSTRIDE + c * 32 + kg * 8]);
#pragma unroll
            for (int ni = 0; ni < 5; ++ni) {
                acc[0][ni] = __builtin_amdgcn_mfma_f32_16x16x32_bf16(A[c & 3][0], bf[ni], acc[0][ni], 0, 0, 0);
                acc[1][ni] = __builtin_amdgcn_mfma_f32_16x16x32_bf16(A[c & 3][1], bf[ni], acc[1][ni], 0, 0, 0);
            }
        }

        if (isOrth) {
#pragma unroll
            for (int mi = 0; mi < 2; ++mi) {
                int rb = mb * 128 + wv * 32 + mi * 16 + kg * 4;
#pragma unroll
                for (int ni = 0; ni < 5; ++ni) {
                    int col = pb * 80 + ni * 16 + l15;
#pragma unroll
                    for (int jj = 0; jj < 4; ++jj) {
                        if (rb + jj == col) continue;
                        float t = (fabsf(acc[mi][ni][jj]) - 0.3f) * (1.0f / 0.70001f);
                        if (t > 0.0f) orthpart += t * t;
                    }
                }
            }
            break;
        }

        const int wbase = (mb * 128) / 25;
#pragma unroll
        for (int mi = 0; mi < 2; ++mi) {
            int f0 = mb * 128 + wv * 32 + mi * 16 + kg * 4;
            int w0 = f0 / 25, w3 = (f0 + 3) / 25;
            int wsplit = w3 * 25;
#pragma unroll
            for (int ni = 0; ni < 5; ++ni) {
                int pc = ni * 16 + l15;
                float p0 = -1e30f, p1 = -1e30f, n0 = -1e30f, n1 = -1e30f;
#pragma unroll
                for (int jj = 0; jj < 4; ++jj) {
                    float v = acc[mi][ni][jj];
                    if (f0 + jj < wsplit) { p0 = fmaxf(p0, v); n0 = fmaxf(n0, -v); }
                    else                 { p1 = fmaxf(p1, v); n1 = fmaxf(n1, -v); }
                }
                atomicMax(&pool[(0 * 7 + (w3 - wbase)) * 80 + pc], okey(p1));
                atomicMax(&pool[(1 * 7 + (w3 - wbase)) * 80 + pc], okey(n1));
                if (w0 != w3) {
                    atomicMax(&pool[(0 * 7 + (w0 - wbase)) * 80 + pc], okey(p0));
                    atomicMax(&pool[(1 * 7 + (w0 - wbase)) * 80 + pc], okey(n0));
                }
            }
        }
        __syncthreads();
        for (int e = tid; e < 1120; e += 256) {
            int pass = e / 560, r2 = e % 560;
            int slot = r2 / 80, pp = r2 % 80;
            gpool[(((size_t)(pass * B_ + b)) * 10 + mb) * 2800 + slot * 400 + pb * 80 + pp] = pool[e];
            pool[e] = OKNEG;
        }
        __syncthreads();
    }

    if (isOrth) {
        for (int off = 32; off; off >>= 1) orthpart += __shfl_down(orthpart, off);
        __syncthreads();
        float* red = (float*)pool;
        if (lane == 0) red[wv] = orthpart;
        __syncthreads();
        if (tid == 0)
            ws[OFF_ORTHB + (nid - 640)] = (red[0] + red[1] + red[2] + red[3]) *
                                          (1.0f / ((float)P_ * (float)P_));
    }
}

// ======= pes: merge exclusive gpool slices -> PES (static-unrolled ILP) =====
__global__ __launch_bounds__(256) void pes_kernel(const unsigned* __restrict__ gpool,
                                                  const int* __restrict__ length,
                                                  float* __restrict__ ws) {
    int idx = blockIdx.x * 256 + threadIdx.x;
    if (idx >= B_ * P_) return;
    int b = idx / P_;
    int p = idx - b * P_;

    float s = 0.f;
#pragma unroll
    for (int pass = 0; pass < 2; ++pass) {
        const unsigned* gp = gpool + ((size_t)(pass * B_ + b)) * 10 * 2800 + p;
        unsigned v[10][7];
#pragma unroll
        for (int mb = 0; mb < 10; ++mb)
#pragma unroll
            for (int sl = 0; sl < 7; ++sl)
                v[mb][sl] = gp[mb * 2800 + sl * 400];
#pragma unroll
        for (int w = 0; w < 48; ++w) {
            int a = 25 * w - 127;
            int mb_lo = (a <= 0) ? 0 : ((a + 127) >> 7);
            int mb_hi = (25 * w + 24) >> 7;
            if (mb_hi > 9) mb_hi = 9;
            unsigned k = 0u;
#pragma unroll
            for (int mb = 0; mb < 10; ++mb) {
                if (mb < mb_lo || mb > mb_hi) continue;
                int slot = w - (mb * 128) / 25;
                unsigned vv = v[mb][slot];
                k = (vv > k) ? vv : k;
            }
            s += dekey(k);
        }
    }
    float rsap = 1.0f / (float)(length[b] / STRIDE_);
    ws[OFF_PES + b * P_ + p] = s * 0.5f * rsap;
}

// ======= graphs_row: write-once row-gather (no pre-zero, no global atomics) ==
__global__ __launch_bounds__(256) void graphs_row_kernel(const float* __restrict__ ws,
                                                         float* __restrict__ out) {
    __shared__ float rowbuf[8 * 200];
    __shared__ int   ki[400][4];
    __shared__ float kv[400][4];
    __shared__ float el[400];

    const int tid = threadIdx.x;
    const int b = blockIdx.x / 25;
    const int n0 = (blockIdx.x % 25) * 8;

    for (int i = tid; i < 1600; i += 256) rowbuf[i] = 0.f;
    for (int p = tid; p < 400; p += 256) {
        *(int4*)ki[p] = ((const int4*)(ws + OFF_KEYIDX))[p];
        *(float4*)kv[p] = ((const float4*)(ws + OFF_KEYVAL))[p];
        el[p] = ws[OFF_PES + b * P_ + p];
    }
    __syncthreads();

    for (int p = tid; p < 400; p += 256) {
        float e = el[p];
#pragma unroll
        for (int a = 0; a < 3; ++a) {
            int n = ki[p][a];
            if (n < n0 || n >= n0 + 8) continue;
            float va = kv[p][a] * e;
#pragma unroll
            for (int c = 0; c < 3; ++c) {
                float scale = (a == c) ? 1.0f : 6.0f;
                atomicAdd(&rowbuf[(n - n0) * 200 + ki[p][c]], va * kv[p][c] * scale);
            }
        }
    }
    __syncthreads();

    f4v* dst = (f4v*)(out + (size_t)b * N_ * N_ + (size_t)n0 * N_);
    const f4v* srcb = (const f4v*)rowbuf;
    for (int i = tid; i < 400; i += 256)
        __builtin_nontemporal_store(srcb[i], dst + i);

    if (blockIdx.x == 0 && tid == 0) {
        float sn = 0.f;
        for (int i = 0; i < PAT_BLKS; ++i) sn += ws[OFF_NORMB + i];
        float so = 0.f;
        for (int i = 0; i < 20; ++i) so += ws[OFF_ORTHB + i];
        out[(size_t)B_ * N_ * N_] = sn;
        out[(size_t)B_ * N_ * N_ + 1] = so;
    }
}

// ---------------- fallback path (fp32, ws-size independent) -----------------
__global__ __launch_bounds__(256) void main_kernel(const float* __restrict__ x,
                                                   const int* __restrict__ length,
                                                   const float* __restrict__ ws,
                                                   float* __restrict__ pes) {
    __shared__ float xs[N_][STRIDE_ + 1];
    __shared__ float rnorm[STRIDE_];
    __shared__ float poolp[P_][5];
    __shared__ float pooln[P_][5];

    int w = blockIdx.x;
    int b = blockIdx.y;
    const float* xb = x + (size_t)b * N_ * T_ + (size_t)w * STRIDE_;

    for (int i = threadIdx.x; i < N_ * STRIDE_; i += 256) {
        int n = i / STRIDE_;
        int t = i - n * STRIDE_;
        xs[n][t] = xb[n * T_ + t];
    }
    __syncthreads();

    if (threadIdx.x < STRIDE_) {
        float ssf = 0.0f;
        for (int n = 0; n < N_; n++) { float vv = xs[n][threadIdx.x]; ssf += vv * vv; }
        rnorm[threadIdx.x] = 1.0f / sqrtf(ssf + EPS_);
    }
    __syncthreads();

    int pt = threadIdx.x % 50;
    int tt = threadIdx.x / 50;

    if (tt < 5) {
        float acc[8][5];
#pragma unroll
        for (int i = 0; i < 8; i++)
#pragma unroll
            for (int j = 0; j < 5; j++) acc[i][j] = 0.0f;

        const float4* np4 = (const float4*)(ws + OFF_NPATT);
        int pbq = pt * 2;
        for (int n = 0; n < N_; n++) {
            float4 q0 = np4[n * (P_ / 4) + pbq];
            float4 q1 = np4[n * (P_ / 4) + pbq + 1];
            float qa[8] = { q0.x, q0.y, q0.z, q0.w, q1.x, q1.y, q1.z, q1.w };
            float xv0 = xs[n][tt * 5 + 0];
            float xv1 = xs[n][tt * 5 + 1];
            float xv2 = xs[n][tt * 5 + 2];
            float xv3 = xs[n][tt * 5 + 3];
            float xv4 = xs[n][tt * 5 + 4];
#pragma unroll
            for (int i = 0; i < 8; i++) {
                acc[i][0] += qa[i] * xv0;
                acc[i][1] += qa[i] * xv1;
                acc[i][2] += qa[i] * xv2;
                acc[i][3] += qa[i] * xv3;
                acc[i][4] += qa[i] * xv4;
            }
        }
#pragma unroll
        for (int i = 0; i < 8; i++) {
            float pm = -1e30f, nm = -1e30f;
#pragma unroll
            for (int j = 0; j < 5; j++) {
                float s = acc[i][j] * rnorm[tt * 5 + j];
                pm = fmaxf(pm, s);
                nm = fmaxf(nm, -s);
            }
            poolp[pt * 8 + i][tt] = pm;
            pooln[pt * 8 + i][tt] = nm;
        }
    }
    __syncthreads();

    float rsap = 1.0f / (float)(length[b] / STRIDE_);
    for (int p = threadIdx.x; p < P_; p += 256) {
        float pm = poolp[p][0], nm = pooln[p][0];
#pragma unroll
        for (int q = 1; q < 5; q++) {
            pm = fmaxf(pm, poolp[p][q]);
            nm = fmaxf(nm, pooln[p][q]);
        }
        atomicAdd(&pes[b * P_ + p], (pm + nm) * 0.5f * rsap);
    }
}

__global__ __launch_bounds__(256) void fb_graphs_kernel(const float* __restrict__ ws,
                                                        float* __restrict__ out) {
    int idx = blockIdx.x * 256 + threadIdx.x;
    if (idx == 0) {
        out[(size_t)B_ * N_ * N_] = ws[OFF_NORM];
        out[(size_t)B_ * N_ * N_ + 1] = ws[OFF_ORTH];
    }
    if (idx >= B_ * P_) return;
    int b = idx / P_;
    int p = idx - b * P_;
    float e = ws[OFF_PES + b * P_ + p];
    const float* keyval = ws + OFF_KEYVAL;
    const int* keyidx = (const int*)(ws + OFF_KEYIDX);
    float va[3] = { keyval[p * 4 + 0], keyval[p * 4 + 1], keyval[p * 4 + 2] };
    int ia[3] = { keyidx[p * 4 + 0], keyidx[p * 4 + 1], keyidx[p * 4 + 2] };
    float* g = out + (size_t)b * N_ * N_;
#pragma unroll
    for (int a = 0; a < 3; a++)
#pragma unroll
        for (int c = 0; c < 3; c++) {
            float scale = (ia[a] == ia[c]) ? 1.0f : 6.0f;
            atomicAdd(&g[ia[a] * N_ + ia[c]], va[a] * va[c] * e * scale);
        }
}

__global__ __launch_bounds__(64) void pat_kernel(const float* __restrict__ patterns,
                                                 float* __restrict__ ws) {
    float d2 = pat_body(patterns, ws, blockIdx.x, threadIdx.x & 63);
    if (threadIdx.x == 0) atomicAdd(ws + OFF_NORM, d2);
}
__global__ __launch_bounds__(256) void orth_kernel(float* __restrict__ ws) {
    __shared__ float rowi[N_];
    __shared__ float red[256];
    const float* npatT = ws + OFF_NPATT;
    int i = blockIdx.x;
    for (int k = threadIdx.x; k < N_; k += 256) rowi[k] = npatT[k * P_ + i];
    __syncthreads();
    float partial = 0.0f;
    for (int j = threadIdx.x; j < P_; j += 256) {
        if (j == i) continue;
        float s = 0.0f;
        for (int k = 0; k < N_; k++) s += rowi[k] * npatT[k * P_ + j];
        float t = (fabsf(s) - 0.3f) * (1.0f / 0.70001f);
        if (t > 0.0f) partial += t * t;
    }
    red[threadIdx.x] = partial;
    __syncthreads();
    for (int sft = 128; sft; sft >>= 1) {
        if (threadIdx.x < sft) red[threadIdx.x] += red[threadIdx.x + sft];
        __syncthreads();
    }
    if (threadIdx.x == 0)
        atomicAdd(ws + OFF_ORTH, red[0] * (1.0f / ((float)P_ * (float)P_)));
}

extern "C" void kernel_launch(void* const* d_in, const int* in_sizes, int n_in,
                              void* d_out, int out_size, void* d_ws, size_t ws_size,
                              hipStream_t stream) {
    const float* x = (const float*)d_in[0];
    const float* patterns = (const float*)d_in[1];
    const int* length = (const int*)d_in[2];
    float* out = (float*)d_out;
    float* ws = (float*)d_ws;

    if (ws_size >= (size_t)WS_FAST_FLOATS * sizeof(float)) {
        unsigned* gpool = (unsigned*)(ws + OFF_GPOOL);
        prep_kernel<<<PREP_BLKS, 256, 0, stream>>>(x, patterns, ws);
        work_kernel<<<660, 256, 0, stream>>>(ws, gpool);
        pes_kernel<<<(B_ * P_ + 255) / 256, 256, 0, stream>>>(gpool, length, ws);
        graphs_row_kernel<<<B_ * 25, 256, 0, stream>>>(ws, out);
    } else {
        (void)hipMemsetAsync(d_out, 0, (size_t)B_ * N_ * N_ * sizeof(float), stream);
        (void)hipMemsetAsync(ws + OFF_PES, 0, (size_t)(B_ * P_) * sizeof(float), stream);
        (void)hipMemsetAsync(ws + OFF_NORM, 0, sizeof(float), stream);
        (void)hipMemsetAsync(ws + OFF_ORTH, 0, sizeof(float), stream);
        pat_kernel<<<P_, 64, 0, stream>>>(patterns, ws);
        orth_kernel<<<P_, 256, 0, stream>>>(ws);
        main_kernel<<<dim3(T_ / STRIDE_, B_), 256, 0, stream>>>(x, length, ws, ws + OFF_PES);
        fb_graphs_kernel<<<(B_ * P_ + 255) / 256, 256, 0, stream>>>(ws, out);
    }
}